// Round 4
// baseline (932.007 us; speedup 1.0000x reference)
//
#include <hip/hip_runtime.h>

typedef unsigned char u8;
typedef unsigned short u16;
typedef float f32x4 __attribute__((ext_vector_type(4)));

#define C_DIM 640
#define HW_DIM 441
#define QN 75
#define SN 25
#define WAYS 5
#define MROWS 33075   // 75*441
#define MPAD  33152   // 259*128
#define MBLK  259
#define NWAY  2205    // 5*441
#define NPAD  2304    // 18*128
#define NTILES 18
#define NPH   90      // 18 nt * 5 kt (BK = 128 fp8 bytes)
#define SCL   16.0f   // fp8 pre-scale (lifts values out of subnormal range)
#define INV_SCL2 (1.0f / (SCL * SCL))

__device__ __forceinline__ void glds16(const void* g, void* l) {
  __builtin_amdgcn_global_load_lds(
      (__attribute__((address_space(1))) unsigned int*)g,
      (__attribute__((address_space(3))) unsigned int*)l, 16, 0, 0);
}

__device__ __forceinline__ unsigned pk4_fp8(float a, float b, float c, float d) {
  unsigned v = 0;
  v = __builtin_amdgcn_cvt_pk_fp8_f32(a, b, v, false);  // bytes 0,1
  v = __builtin_amdgcn_cvt_pk_fp8_f32(c, d, v, true);   // bytes 2,3
  return v;
}

// ---------------------------------------------------------------------------
// Zero pad rows of A/B (fp8, bytes) and the output accumulator.
// ---------------------------------------------------------------------------
__global__ void zero_pad(u8* __restrict__ A8, u8* __restrict__ S8,
                         float* __restrict__ out) {
  int i = blockIdx.x * 256 + threadIdx.x;
  if (i < 49280) {                                  // (MPAD-MROWS)*640 bytes
    A8[(size_t)MROWS * C_DIM + i] = 0;
    return;
  }
  i -= 49280;
  if (i < 316800) {                                 // 5*(NPAD-NWAY)*640 bytes
    const int w = i / 63360;
    const int r = i % 63360;
    S8[((size_t)w * NPAD + NWAY) * C_DIM + r] = 0;
    return;
  }
  i -= 316800;
  if (i < QN * WAYS) out[i] = 0.f;
}

// ---------------------------------------------------------------------------
// Normalize each (img, hw) descriptor over C, scale by SCL, emit fp8 e4m3,
// transposed to [row][c] (c contiguous, 640 B/row).
// Queries: row = q*441+m. Support: row = way*2304 + shot*441 + m.
// ---------------------------------------------------------------------------
__global__ __launch_bounds__(256)
void prep_norm_transpose(const float* __restrict__ src, u8* __restrict__ dst,
                         int support) {
  const int bid = blockIdx.x;
  const int img = bid / 7;
  const int mt = bid % 7;
  const int m0 = mt * 64;
  const int t = threadIdx.x;
  const int mloc = t & 63;
  const int cpart = t >> 6;                 // 0..3
  const int m = m0 + mloc;
  const int m_eff = (m < HW_DIM) ? m : (HW_DIM - 1);
  const float* base = src + (size_t)img * (C_DIM * HW_DIM);

  // ---- phase 1: sum of squares over C (4-way c-split) ----
  float ss = 0.f;
  const int c0 = cpart * 160;
  for (int c = c0; c < c0 + 160; ++c) {
    float v = base[(size_t)c * HW_DIM + m_eff];
    ss += v * v;
  }
  __shared__ float red[256];
  __shared__ float inv[64];
  red[t] = ss;
  __syncthreads();
  if (t < 64) {
    float s4 = red[t] + red[t + 64] + red[t + 128] + red[t + 192];
    inv[t] = rsqrtf(s4) * SCL;
  }
  __syncthreads();

  size_t drow0;
  if (support) {
    const int w = img / 5, shot = img % 5;
    drow0 = (size_t)w * NPAD + (size_t)shot * HW_DIM;
  } else {
    drow0 = (size_t)img * HW_DIM;
  }

  // ---- phase 2: tiled transpose through LDS, normalize + cvt to fp8 ----
  __shared__ __align__(16) u8 T[64][80];    // 64 data + 16 pad, 16B-aligned rows
  const float iv = inv[mloc];
  const int mw = t >> 2;
  const int cg = t & 3;
  const int m_out = m0 + mw;

  for (int ct = 0; ct < 10; ++ct) {
    float f[16];
#pragma unroll
    for (int ci = 0; ci < 16; ++ci) {
      const int c = ct * 64 + cpart * 16 + ci;
      f[ci] = base[(size_t)c * HW_DIM + m_eff] * iv;
    }
    __syncthreads();                        // previous tile fully consumed
    uint4 w;
    w.x = pk4_fp8(f[0], f[1], f[2], f[3]);
    w.y = pk4_fp8(f[4], f[5], f[6], f[7]);
    w.z = pk4_fp8(f[8], f[9], f[10], f[11]);
    w.w = pk4_fp8(f[12], f[13], f[14], f[15]);
    *(uint4*)&T[mloc][cpart * 16] = w;
    __syncthreads();
    if (m_out < HW_DIM) {
      const uint4 v = *(const uint4*)&T[mw][cg * 16];
      *(uint4*)(dst + (drow0 + m_out) * C_DIM + ct * 64 + cg * 16) = v;
    }
  }
}

// ---------------------------------------------------------------------------
// Fused cosine-sim GEMM (fp8) + per-row top-3 + sum.
// A tile (128 rows x full K=640 fp8 = 80 KB) persistent in LDS, staged ONCE.
// B streamed per phase (BK=128 bytes) through a 2x16 KB double buffer,
// prefetched one full compute phase (~1300 cyc) ahead -> vmcnt drain covered.
// 1 block/CU (116 KB LDS), 256 threads = 4 waves in 2x2 (wave tile 64x64).
// Grid: 5 ways * 259 m-chunks, way-major (B way = 1.44 MB fp8, L2-resident).
// ---------------------------------------------------------------------------
__global__ __launch_bounds__(256, 1)
void simtopk(const u8* __restrict__ A8, const u8* __restrict__ S8,
             float* __restrict__ out) {
  __shared__ __align__(16) u8 As[128 * 640];        // 80 KB persistent A
  __shared__ __align__(16) u8 Bs[2][128 * 128];     // 32 KB B double buffer
  __shared__ float part[2][128][4];                 // 4 KB epilogue
  __shared__ float qsum[2];

  const int bid = blockIdx.x;
  const int way = bid / MBLK;
  const int mc = bid % MBLK;
  const int R0 = mc * 128;
  const int tid = threadIdx.x;
  const int lane = tid & 63;
  const int wv = tid >> 6;
  const int wm = (wv >> 1) * 64;
  const int wn = (wv & 1) * 64;
  const int l15 = lane & 15;
  const int l4 = lane >> 4;

  if (tid < 2) qsum[tid] = 0.f;

  const u8* Sway = S8 + (size_t)way * NPAD * C_DIM;

  // ---- stage A once: 128 rows x 640 B, XOR-swizzled (16B quads, groups of 8)
  // dense 5-instruction pattern per 8-row octet (8*640 = 5*1024 B)
  unsigned aoffs[5];
#pragma unroll
  for (int i = 0; i < 5; ++i) {
    const int lin = i * 64 + lane;
    const int row = lin / 40;                       // 40 quads of 16B per row
    const int quad = lin % 40;
    const int sq = (quad & ~7) | ((quad & 7) ^ (row & 7));
    aoffs[i] = (unsigned)(row * 640 + sq * 16);
  }
  const u8* Ab = A8 + (size_t)R0 * C_DIM;
#pragma unroll
  for (int o = 0; o < 4; ++o) {
    const int oct = wv * 4 + o;                     // this wave's octets
#pragma unroll
    for (int i = 0; i < 5; ++i)
      glds16(Ab + (unsigned)oct * 5120 + aoffs[i], As + oct * 5120 + i * 1024);
  }

  // ---- B staging: per instruction 64 lanes x 16B = 8 rows of 128 B
  const unsigned brow_off =
      (unsigned)((lane >> 3) * 640 + (((lane & 7) ^ (lane >> 3)) * 16));
  // prologue: phase 0 (nt=0, kt=0) into buffer 0
#pragma unroll
  for (int j = 0; j < 4; ++j) {
    const int r8 = wv * 32 + j * 8;
    glds16(Sway + (unsigned)r8 * 640 + brow_off, Bs[0] + r8 * 128);
  }

  f32x4 acc[4][4];
  const f32x4 z4 = {0.f, 0.f, 0.f, 0.f};
#pragma unroll
  for (int mi = 0; mi < 4; ++mi)
#pragma unroll
    for (int ni = 0; ni < 4; ++ni) acc[mi][ni] = z4;

  float t0[16], t1[16], t2[16];             // per-lane top-3, 16 row slots
#pragma unroll
  for (int r = 0; r < 16; ++r) { t0[r] = -1e30f; t1[r] = -1e30f; t2[r] = -1e30f; }

  int p = 0;
  for (int ph = 0; ph < NPH; ++ph) {
    const int nt = ph / 5, kt = ph % 5;
    __syncthreads();  // own-vmcnt drain in every wave: B[p] (and A on ph=0)
                      // fully in LDS; phase ph-1's readers of B[p^1] done.
    if (ph + 1 < NPH) {
      const int ph1 = ph + 1;
      const int nt1 = ph1 / 5, kt1 = ph1 % 5;
      const unsigned bof = (unsigned)nt1 * (128 * C_DIM) + (unsigned)(kt1 * 128);
#pragma unroll
      for (int j = 0; j < 4; ++j) {
        const int r8 = wv * 32 + j * 8;
        glds16(Sway + (unsigned)r8 * 640 + brow_off + bof, Bs[p ^ 1] + r8 * 128);
      }
    }

    const u8* Bp = Bs[p];
    const int ktb = kt * 128;
#pragma unroll
    for (int s = 0; s < 4; ++s) {
      const int qp = (s * 2 + (l4 >> 1)) ^ (l15 & 7);  // same swizzle A and B
      const int sub = (l4 & 1) * 8;
      long long af[4], bf[4];
#pragma unroll
      for (int mi = 0; mi < 4; ++mi) {
        const int row = wm + mi * 16 + l15;
        af[mi] = *(const long long*)(As + row * 640 + ktb + qp * 16 + sub);
      }
#pragma unroll
      for (int ni = 0; ni < 4; ++ni) {
        const int row = wn + ni * 16 + l15;
        bf[ni] = *(const long long*)(Bp + row * 128 + qp * 16 + sub);
      }
#pragma unroll
      for (int mi = 0; mi < 4; ++mi)
#pragma unroll
        for (int ni = 0; ni < 4; ++ni)
          acc[mi][ni] = __builtin_amdgcn_mfma_f32_16x16x32_fp8_fp8(
              af[mi], bf[ni], acc[mi][ni], 0, 0, 0);
    }

    if (kt == 4) {
      // end of this nt: branchless top-3 insert, then re-zero acc
      const bool lastTile = (nt == NTILES - 1);
#pragma unroll
      for (int ni = 0; ni < 4; ++ni) {
        const int ncol = nt * 128 + wn + ni * 16 + l15;
        const bool bad = lastTile && (ncol >= NWAY);
#pragma unroll
        for (int mi = 0; mi < 4; ++mi)
#pragma unroll
          for (int i = 0; i < 4; ++i) {
            float v = acc[mi][ni][i];
            if (bad) v = -1e30f;
            const int r = mi * 4 + i;
            t2[r] = fmaxf(t2[r], fminf(v, t1[r]));
            t1[r] = fmaxf(t1[r], fminf(v, t0[r]));
            t0[r] = fmaxf(t0[r], v);
            acc[mi][ni][i] = 0.f;
          }
      }
    }
    p ^= 1;
  }

  // merge top-3 across the 16 column-lanes (same rows live in all l15 lanes)
#pragma unroll
  for (int d = 1; d <= 8; d <<= 1) {
#pragma unroll
    for (int r = 0; r < 16; ++r) {
      const float o0 = __shfl_xor(t0[r], d);
      const float o1 = __shfl_xor(t1[r], d);
      const float o2 = __shfl_xor(t2[r], d);
      t2[r] = fmaxf(t2[r], fminf(o0, t1[r]));
      t1[r] = fmaxf(t1[r], fminf(o0, t0[r]));
      t0[r] = fmaxf(t0[r], o0);
      t2[r] = fmaxf(t2[r], fminf(o1, t1[r]));
      t1[r] = fmaxf(t1[r], fminf(o1, t0[r]));
      t0[r] = fmaxf(t0[r], o1);
      t2[r] = fmaxf(t2[r], fminf(o2, t1[r]));
      t1[r] = fmaxf(t1[r], fminf(o2, t0[r]));
      t0[r] = fmaxf(t0[r], o2);
    }
  }

  // cross-wave merge (wn=0 half vs wn=64 half) through LDS
  if (l15 == 0) {
    const int pp = wv & 1;
#pragma unroll
    for (int r = 0; r < 16; ++r) {
      const int mi = r >> 2, i = r & 3;
      const int row_local = wm + mi * 16 + l4 * 4 + i;
      part[pp][row_local][0] = t0[r];
      part[pp][row_local][1] = t1[r];
      part[pp][row_local][2] = t2[r];
    }
  }
  __syncthreads();
  if (tid < 128) {
    const int grow = R0 + tid;
    if (grow < MROWS) {
      float a0 = part[0][tid][0], a1 = part[0][tid][1], a2 = part[0][tid][2];
      const float b0 = part[1][tid][0];
      const float b1 = part[1][tid][1];
      const float b2 = part[1][tid][2];
      a2 = fmaxf(a2, fminf(b0, a1)); a1 = fmaxf(a1, fminf(b0, a0)); a0 = fmaxf(a0, b0);
      a2 = fmaxf(a2, fminf(b1, a1)); a1 = fmaxf(a1, fminf(b1, a0)); a0 = fmaxf(a0, b1);
      a2 = fmaxf(a2, fminf(b2, a1)); a1 = fmaxf(a1, fminf(b2, a0)); a0 = fmaxf(a0, b2);
      const float rs = (a0 + a1 + a2) * INV_SCL2;   // undo fp8 pre-scale
      const int qq = grow / HW_DIM;
      atomicAdd(&qsum[qq - (R0 / HW_DIM)], rs);     // block spans <= 2 q's
    }
  }
  __syncthreads();
  if (tid < 2) {
    const int qq = R0 / HW_DIM + tid;
    if (qq < QN) atomicAdd(out + qq * WAYS + way, qsum[tid]);
  }
}

// ---------------------------------------------------------------------------
extern "C" void kernel_launch(void* const* d_in, const int* in_sizes, int n_in,
                              void* d_out, int out_size, void* d_ws, size_t ws_size,
                              hipStream_t stream) {
  const float* x1 = (const float*)d_in[0];
  const float* x2 = (const float*)d_in[1];
  float* out = (float*)d_out;
  u8* A8 = (u8*)d_ws;                                        // MPAD x 640 fp8
  u8* S8 = (u8*)d_ws + (size_t)MPAD * C_DIM;                 // 5 x NPAD x 640

  hipLaunchKernelGGL(zero_pad, dim3(1432), dim3(256), 0, stream, A8, S8, out);
  hipLaunchKernelGGL(prep_norm_transpose, dim3(QN * 7), dim3(256), 0, stream,
                     x1, A8, 0);
  hipLaunchKernelGGL(prep_norm_transpose, dim3(SN * 7), dim3(256), 0, stream,
                     x2, S8, 1);
  hipLaunchKernelGGL(simtopk, dim3(WAYS * MBLK), dim3(256), 0, stream,
                     A8, S8, out);
}

// Round 5
// 634.504 us; speedup vs baseline: 1.4689x; 1.4689x over previous
//
#include <hip/hip_runtime.h>

typedef unsigned char u8;
typedef float f32x4 __attribute__((ext_vector_type(4)));

#define C_DIM 640
#define HW_DIM 441
#define QN 75
#define SN 25
#define WAYS 5
#define MROWS 33075     // 75*441
#define MCH   96        // m rows per block
#define MBLK  345       // ceil(33075/96)
#define MPAD  33120     // MBLK*MCH
#define NWAY  2205      // 5*441
#define NPAD  2304      // 18*128 = 6*384
#define BN    384       // block n-tile
#define NT    6         // NPAD/BN
#define SCL   16.0f     // fp8 pre-scale
#define INV_SCL2 (1.0f / (SCL * SCL))

__device__ __forceinline__ void glds16(const void* g, void* l) {
  __builtin_amdgcn_global_load_lds(
      (__attribute__((address_space(1))) unsigned int*)g,
      (__attribute__((address_space(3))) unsigned int*)l, 16, 0, 0);
}

__device__ __forceinline__ unsigned pk4_fp8(float a, float b, float c, float d) {
  unsigned v = 0;
  v = __builtin_amdgcn_cvt_pk_fp8_f32(a, b, v, false);  // bytes 0,1
  v = __builtin_amdgcn_cvt_pk_fp8_f32(c, d, v, true);   // bytes 2,3
  return v;
}

// ---------------------------------------------------------------------------
// Zero pad rows of A/B (fp8 bytes) and the output accumulator.
// ---------------------------------------------------------------------------
__global__ void zero_pad(u8* __restrict__ A8, u8* __restrict__ S8,
                         float* __restrict__ out) {
  int i = blockIdx.x * 256 + threadIdx.x;
  if (i < 28800) {                                  // (MPAD-MROWS)*640 bytes
    A8[(size_t)MROWS * C_DIM + i] = 0;
    return;
  }
  i -= 28800;
  if (i < 316800) {                                 // 5*(NPAD-NWAY)*640 bytes
    const int w = i / 63360;
    const int r = i % 63360;
    S8[((size_t)w * NPAD + NWAY) * C_DIM + r] = 0;
    return;
  }
  i -= 316800;
  if (i < QN * WAYS) out[i] = 0.f;
}

// ---------------------------------------------------------------------------
// Normalize each (img, hw) descriptor over C, scale by SCL, emit fp8 e4m3,
// transposed to [row][c] (c contiguous, 640 B/row). (unchanged from R4)
// ---------------------------------------------------------------------------
__global__ __launch_bounds__(256)
void prep_norm_transpose(const float* __restrict__ src, u8* __restrict__ dst,
                         int support) {
  const int bid = blockIdx.x;
  const int img = bid / 7;
  const int mt = bid % 7;
  const int m0 = mt * 64;
  const int t = threadIdx.x;
  const int mloc = t & 63;
  const int cpart = t >> 6;                 // 0..3
  const int m = m0 + mloc;
  const int m_eff = (m < HW_DIM) ? m : (HW_DIM - 1);
  const float* base = src + (size_t)img * (C_DIM * HW_DIM);

  float ss = 0.f;
  const int c0 = cpart * 160;
  for (int c = c0; c < c0 + 160; ++c) {
    float v = base[(size_t)c * HW_DIM + m_eff];
    ss += v * v;
  }
  __shared__ float red[256];
  __shared__ float inv[64];
  red[t] = ss;
  __syncthreads();
  if (t < 64) {
    float s4 = red[t] + red[t + 64] + red[t + 128] + red[t + 192];
    inv[t] = rsqrtf(s4) * SCL;
  }
  __syncthreads();

  size_t drow0;
  if (support) {
    const int w = img / 5, shot = img % 5;
    drow0 = (size_t)w * NPAD + (size_t)shot * HW_DIM;
  } else {
    drow0 = (size_t)img * HW_DIM;
  }

  __shared__ __align__(16) u8 T[64][80];
  const float iv = inv[mloc];
  const int mw = t >> 2;
  const int cg = t & 3;
  const int m_out = m0 + mw;

  for (int ct = 0; ct < 10; ++ct) {
    float f[16];
#pragma unroll
    for (int ci = 0; ci < 16; ++ci) {
      const int c = ct * 64 + cpart * 16 + ci;
      f[ci] = base[(size_t)c * HW_DIM + m_eff] * iv;
    }
    __syncthreads();
    uint4 w;
    w.x = pk4_fp8(f[0], f[1], f[2], f[3]);
    w.y = pk4_fp8(f[4], f[5], f[6], f[7]);
    w.z = pk4_fp8(f[8], f[9], f[10], f[11]);
    w.w = pk4_fp8(f[12], f[13], f[14], f[15]);
    *(uint4*)&T[mloc][cpart * 16] = w;
    __syncthreads();
    if (m_out < HW_DIM) {
      const uint4 v = *(const uint4*)&T[mw][cg * 16];
      *(uint4*)(dst + (drow0 + m_out) * C_DIM + ct * 64 + cg * 16) = v;
    }
  }
}

// ---------------------------------------------------------------------------
// Fused cosine-sim GEMM (fp8) + per-row top-3 + sum.
// Round-5 shape: 512 threads = 8 waves (2/SIMD), block tile 96x384,
// wave tile 48x96 (2 m-halves x 4 n-quarters). A (96x640 = 60 KB) persistent,
// staged once. B double-buffered 2x48 KB, prefetched one phase (~2800 cyc of
// MFMA) ahead. kt unrolled, frag addrs precomputed. Grid 5*345 (96% packing).
// ---------------------------------------------------------------------------
__global__ __launch_bounds__(512, 2)
void simtopk(const u8* __restrict__ A8, const u8* __restrict__ S8,
             float* __restrict__ out) {
  __shared__ __align__(16) u8 As[MCH * C_DIM];      // 60 KB persistent A
  __shared__ __align__(16) u8 Bs[2][BN * 128];      // 96 KB B double buffer
  __shared__ float qsum[2];

  const int bid = blockIdx.x;
  const int way = bid / MBLK;
  const int mc = bid % MBLK;
  const int R0 = mc * MCH;
  const int tid = threadIdx.x;
  const int lane = tid & 63;
  const int wv = tid >> 6;                  // 0..7
  const int wm = (wv >> 2) * 48;            // m-half base (0 / 48)
  const int wn = (wv & 3) * 96;             // n-quarter base (0/96/192/288)
  const int l15 = lane & 15;
  const int l4 = lane >> 4;

  if (tid < 2) qsum[tid] = 0.f;

  const u8* Sway = S8 + (size_t)way * NPAD * C_DIM;
  const u8* Ab = A8 + (size_t)R0 * C_DIM;

  // ---- stage A once: 12 octets (8 rows) x 5 instrs = 60 wave-instructions,
  // XOR-swizzled quads (16B) within 8-quad groups, swizzle on source side.
#pragma unroll
  for (int i = 0; i < 8; ++i) {
    const int id = wv * 8 + i;
    if (id < 60) {
      const int oct = id / 5, i2 = id % 5;
      const int lin = i2 * 64 + lane;
      const int row = lin / 40;             // 0..7 within octet
      const int quad = lin % 40;
      const int sq = (quad & ~7) | ((quad & 7) ^ (row & 7));
      glds16(Ab + (unsigned)oct * 5120 + (unsigned)(row * 640 + sq * 16),
             As + oct * 5120 + i2 * 1024);
    }
  }

  // ---- B staging: strip = 8 rows x 128 B = 1 KB per instruction;
  // 48 strips per phase, 6 per wave. Source-side XOR swizzle.
  const unsigned brow =
      (unsigned)((lane >> 3) * 640 + (((lane & 7) ^ (lane >> 3)) * 16));
  // prologue: phase (nt=0, kt=0) into buffer 0
#pragma unroll
  for (int j = 0; j < 6; ++j) {
    const int st = wv * 6 + j;
    glds16(Sway + (unsigned)st * (8 * 640) + brow, Bs[0] + st * 1024);
  }

  // ---- precomputed frag addresses (LDS byte offsets) ----
  int aBase[3][4], bBase[6][4];
#pragma unroll
  for (int s = 0; s < 4; ++s) {
    const int phys = ((2 * s + (l4 >> 1)) ^ (l15 & 7)) * 16 + (l4 & 1) * 8;
#pragma unroll
    for (int mi = 0; mi < 3; ++mi)
      aBase[mi][s] = (wm + mi * 16 + l15) * 640 + phys;
#pragma unroll
    for (int ni = 0; ni < 6; ++ni)
      bBase[ni][s] = (wn + ni * 16 + l15) * 128 + phys;
  }

  f32x4 acc[3][6];
  const f32x4 z4 = {0.f, 0.f, 0.f, 0.f};
#pragma unroll
  for (int mi = 0; mi < 3; ++mi)
#pragma unroll
    for (int ni = 0; ni < 6; ++ni) acc[mi][ni] = z4;

  float t0[12], t1[12], t2[12];
#pragma unroll
  for (int r = 0; r < 12; ++r) { t0[r] = -1e30f; t1[r] = -1e30f; t2[r] = -1e30f; }

  int p = 0;
  for (int nt = 0; nt < NT; ++nt) {
#pragma unroll
    for (int kt = 0; kt < 5; ++kt) {
      __syncthreads();  // Bs[p] complete (prefetched last phase); Bs[p^1] free

      if (!(nt == NT - 1 && kt == 4)) {     // prefetch next phase into Bs[p^1]
        const int nt1 = (kt == 4) ? nt + 1 : nt;
        const int kt1 = (kt == 4) ? 0 : kt + 1;
        const unsigned off =
            (unsigned)nt1 * (BN * C_DIM) + (unsigned)(kt1 * 128);
#pragma unroll
        for (int j = 0; j < 6; ++j) {
          const int st = wv * 6 + j;
          glds16(Sway + (unsigned)st * (8 * 640) + brow + off,
                 Bs[p ^ 1] + st * 1024);
        }
      }

      const u8* Bp = Bs[p];
      long long af[3][4];
#pragma unroll
      for (int mi = 0; mi < 3; ++mi)
#pragma unroll
        for (int s = 0; s < 4; ++s)
          af[mi][s] = *(const long long*)(As + aBase[mi][s] + kt * 128);

#pragma unroll
      for (int ni = 0; ni < 6; ++ni) {
        long long bf[4];
#pragma unroll
        for (int s = 0; s < 4; ++s)
          bf[s] = *(const long long*)(Bp + bBase[ni][s]);
#pragma unroll
        for (int s = 0; s < 4; ++s)
#pragma unroll
          for (int mi = 0; mi < 3; ++mi)
            acc[mi][ni] = __builtin_amdgcn_mfma_f32_16x16x32_fp8_fp8(
                af[mi][s], bf[s], acc[mi][ni], 0, 0, 0);
      }
      p ^= 1;
    }

    // end of nt: branchless top-3 insert, re-zero acc
    const bool lastTile = (nt == NT - 1);
#pragma unroll
    for (int ni = 0; ni < 6; ++ni) {
      const int ncol = nt * BN + wn + ni * 16 + l15;
      const bool bad = lastTile && (ncol >= NWAY);
#pragma unroll
      for (int mi = 0; mi < 3; ++mi)
#pragma unroll
        for (int i = 0; i < 4; ++i) {
          float v = acc[mi][ni][i];
          if (bad) v = -1e30f;
          const int r = mi * 4 + i;
          t2[r] = fmaxf(t2[r], fminf(v, t1[r]));
          t1[r] = fmaxf(t1[r], fminf(v, t0[r]));
          t0[r] = fmaxf(t0[r], v);
          acc[mi][ni][i] = 0.f;
        }
    }
  }

  // merge top-3 across the 16 column-lanes (lane bits 0..3 = column)
#pragma unroll
  for (int d = 1; d <= 8; d <<= 1) {
#pragma unroll
    for (int r = 0; r < 12; ++r) {
      const float o0 = __shfl_xor(t0[r], d);
      const float o1 = __shfl_xor(t1[r], d);
      const float o2 = __shfl_xor(t2[r], d);
      t2[r] = fmaxf(t2[r], fminf(o0, t1[r]));
      t1[r] = fmaxf(t1[r], fminf(o0, t0[r]));
      t0[r] = fmaxf(t0[r], o0);
      t2[r] = fmaxf(t2[r], fminf(o1, t1[r]));
      t1[r] = fmaxf(t1[r], fminf(o1, t0[r]));
      t0[r] = fmaxf(t0[r], o1);
      t2[r] = fmaxf(t2[r], fminf(o2, t1[r]));
      t1[r] = fmaxf(t1[r], fminf(o2, t0[r]));
      t0[r] = fmaxf(t0[r], o2);
    }
  }

  // cross-wave merge over the 4 n-quarters, through LDS (aliased into Bs;
  // all tile reads are done). part[nq][row 0..95][4].
  __syncthreads();
  float* part = (float*)&Bs[0][0];
  if (l15 == 0) {
    const int nq = wv & 3;
#pragma unroll
    for (int r = 0; r < 12; ++r) {
      const int mi = r >> 2, i = r & 3;
      const int row_local = wm + mi * 16 + l4 * 4 + i;
      part[(nq * MCH + row_local) * 4 + 0] = t0[r];
      part[(nq * MCH + row_local) * 4 + 1] = t1[r];
      part[(nq * MCH + row_local) * 4 + 2] = t2[r];
    }
  }
  __syncthreads();
  if (tid < MCH) {
    const int grow = R0 + tid;
    if (grow < MROWS) {
      float a0 = part[tid * 4 + 0], a1 = part[tid * 4 + 1], a2 = part[tid * 4 + 2];
#pragma unroll
      for (int nq = 1; nq < 4; ++nq) {
        const float b0 = part[(nq * MCH + tid) * 4 + 0];
        const float b1 = part[(nq * MCH + tid) * 4 + 1];
        const float b2 = part[(nq * MCH + tid) * 4 + 2];
        a2 = fmaxf(a2, fminf(b0, a1)); a1 = fmaxf(a1, fminf(b0, a0)); a0 = fmaxf(a0, b0);
        a2 = fmaxf(a2, fminf(b1, a1)); a1 = fmaxf(a1, fminf(b1, a0)); a0 = fmaxf(a0, b1);
        a2 = fmaxf(a2, fminf(b2, a1)); a1 = fmaxf(a1, fminf(b2, a0)); a0 = fmaxf(a0, b2);
      }
      const float rs = (a0 + a1 + a2) * INV_SCL2;
      const int qq = grow / HW_DIM;
      atomicAdd(&qsum[qq - (R0 / HW_DIM)], rs);     // block spans <= 2 q's
    }
  }
  __syncthreads();
  if (tid < 2) {
    const int qq = R0 / HW_DIM + tid;
    if (qq < QN) atomicAdd(out + qq * WAYS + way, qsum[tid]);
  }
}

// ---------------------------------------------------------------------------
extern "C" void kernel_launch(void* const* d_in, const int* in_sizes, int n_in,
                              void* d_out, int out_size, void* d_ws, size_t ws_size,
                              hipStream_t stream) {
  const float* x1 = (const float*)d_in[0];
  const float* x2 = (const float*)d_in[1];
  float* out = (float*)d_out;
  u8* A8 = (u8*)d_ws;                                        // MPAD x 640 fp8
  u8* S8 = (u8*)d_ws + (size_t)MPAD * C_DIM;                 // 5 x NPAD x 640

  hipLaunchKernelGGL(zero_pad, dim3(1352), dim3(256), 0, stream, A8, S8, out);
  hipLaunchKernelGGL(prep_norm_transpose, dim3(QN * 7), dim3(256), 0, stream,
                     x1, A8, 0);
  hipLaunchKernelGGL(prep_norm_transpose, dim3(SN * 7), dim3(256), 0, stream,
                     x2, S8, 1);
  hipLaunchKernelGGL(simtopk, dim3(WAYS * MBLK), dim3(512), 0, stream,
                     A8, S8, out);
}

// Round 6
// 560.341 us; speedup vs baseline: 1.6633x; 1.1324x over previous
//
#include <hip/hip_runtime.h>

typedef unsigned char u8;
typedef int i32x4 __attribute__((ext_vector_type(4)));
typedef int i32x16 __attribute__((ext_vector_type(16)));

#define C_DIM 640
#define HW_DIM 441
#define QN 75
#define SN 25
#define WAYS 5
#define MROWS 33075     // 75*441
#define MCH   128       // m rows per block
#define MBLK  259       // ceil(33075/128)
#define MPAD  33152     // MBLK*MCH
#define NWAY  2205      // 5*441
#define NPAD  2304      // 18*128 = 9*256
#define BN    256       // block n-tile
#define NT    9         // NPAD/BN
#define INV_Q2 (1.0f / 16129.0f)   // 1/127^2
#define NEGINF (-2147483647 - 1)

__device__ __forceinline__ void glds16(const void* g, void* l) {
  __builtin_amdgcn_global_load_lds(
      (__attribute__((address_space(1))) unsigned int*)g,
      (__attribute__((address_space(3))) unsigned int*)l, 16, 0, 0);
}

// ---------------------------------------------------------------------------
// Zero pad rows of A/B (int8 bytes) and the output accumulator.
// ---------------------------------------------------------------------------
__global__ void zero_pad(u8* __restrict__ A8, u8* __restrict__ S8,
                         float* __restrict__ out) {
  int i = blockIdx.x * 256 + threadIdx.x;
  if (i < 49280) {                                  // (MPAD-MROWS)*640 bytes
    A8[(size_t)MROWS * C_DIM + i] = 0;
    return;
  }
  i -= 49280;
  if (i < 316800) {                                 // 5*(NPAD-NWAY)*640 bytes
    const int w = i / 63360;
    const int r = i % 63360;
    S8[((size_t)w * NPAD + NWAY) * C_DIM + r] = 0;
    return;
  }
  i -= 316800;
  if (i < QN * WAYS) out[i] = 0.f;
}

// ---------------------------------------------------------------------------
// Normalize each (img, hw) descriptor over C, scale by 127, emit int8,
// transposed to [row][c] (c contiguous, 640 B/row).
// Queries: row = q*441+m. Support: row = way*2304 + shot*441 + m.
// ---------------------------------------------------------------------------
__global__ __launch_bounds__(256)
void prep_norm_transpose(const float* __restrict__ src, u8* __restrict__ dst,
                         int support) {
  const int bid = blockIdx.x;
  const int img = bid / 7;
  const int mt = bid % 7;
  const int m0 = mt * 64;
  const int t = threadIdx.x;
  const int mloc = t & 63;
  const int cpart = t >> 6;                 // 0..3
  const int m = m0 + mloc;
  const int m_eff = (m < HW_DIM) ? m : (HW_DIM - 1);
  const float* base = src + (size_t)img * (C_DIM * HW_DIM);

  float ss = 0.f;
  const int c0 = cpart * 160;
  for (int c = c0; c < c0 + 160; ++c) {
    float v = base[(size_t)c * HW_DIM + m_eff];
    ss += v * v;
  }
  __shared__ float red[256];
  __shared__ float inv[64];
  red[t] = ss;
  __syncthreads();
  if (t < 64) {
    float s4 = red[t] + red[t + 64] + red[t + 128] + red[t + 192];
    inv[t] = rsqrtf(s4) * 127.0f;
  }
  __syncthreads();

  size_t drow0;
  if (support) {
    const int w = img / 5, shot = img % 5;
    drow0 = (size_t)w * NPAD + (size_t)shot * HW_DIM;
  } else {
    drow0 = (size_t)img * HW_DIM;
  }

  __shared__ __align__(16) u8 T[64][80];    // 64 data + 16 pad per row
  const float iv = inv[mloc];
  const int mw = t >> 2;
  const int cg = t & 3;
  const int m_out = m0 + mw;

  for (int ct = 0; ct < 10; ++ct) {
    int q[16];
#pragma unroll
    for (int ci = 0; ci < 16; ++ci) {
      const int c = ct * 64 + cpart * 16 + ci;
      q[ci] = __float2int_rn(base[(size_t)c * HW_DIM + m_eff] * iv);
    }
    __syncthreads();                        // previous tile fully consumed
    uint4 w;
    w.x = (q[0] & 255) | ((q[1] & 255) << 8) | ((q[2] & 255) << 16) | ((q[3] & 255) << 24);
    w.y = (q[4] & 255) | ((q[5] & 255) << 8) | ((q[6] & 255) << 16) | ((q[7] & 255) << 24);
    w.z = (q[8] & 255) | ((q[9] & 255) << 8) | ((q[10] & 255) << 16) | ((q[11] & 255) << 24);
    w.w = (q[12] & 255) | ((q[13] & 255) << 8) | ((q[14] & 255) << 16) | ((q[15] & 255) << 24);
    *(uint4*)&T[mloc][cpart * 16] = w;
    __syncthreads();
    if (m_out < HW_DIM) {
      const uint4 v = *(const uint4*)&T[mw][cg * 16];
      *(uint4*)(dst + (drow0 + m_out) * C_DIM + ct * 64 + cg * 16) = v;
    }
  }
}

// ---------------------------------------------------------------------------
// Fused cosine-sim GEMM (int8, mfma_i32_32x32x32_i8) + per-row top-3 + sum.
// Block tile 128x256, 8 waves (2m x 4n), wave tile 64x64 = 2x2 MFMAs of
// 32x32. Frag loads are ds_read_b128 (16 B/lane) with the XOR-quad swizzle
// that measured ZERO bank conflicts in rounds 1-3.
// A (128x640 i8 = 80 KB) persistent in LDS, staged once. B double-buffered
// 2x32 KB, prefetched one full phase ahead (R5's proven scheme).
// Grid: 5 ways * 259 m-chunks, way-major.
// ---------------------------------------------------------------------------
__global__ __launch_bounds__(512, 2)
void simtopk(const u8* __restrict__ A8, const u8* __restrict__ S8,
             float* __restrict__ out) {
  __shared__ __align__(16) u8 As[MCH * C_DIM];      // 80 KB persistent A
  __shared__ __align__(16) u8 Bs[2][BN * 128];      // 64 KB B double buffer
  __shared__ float qsum[2];

  const int bid = blockIdx.x;
  const int way = bid / MBLK;
  const int mc = bid % MBLK;
  const int R0 = mc * MCH;
  const int tid = threadIdx.x;
  const int lane = tid & 63;
  const int wv = tid >> 6;                  // 0..7
  const int wmB = (wv >> 2) * 64;           // wave m base: 0 / 64
  const int wnB = (wv & 3) * 64;            // wave n base: 0/64/128/192
  const int r5 = lane & 31;
  const int h = lane >> 5;                  // k-half selector in frag layout

  if (tid < 2) qsum[tid] = 0.f;

  const u8* Sway = S8 + (size_t)way * NPAD * C_DIM;
  const u8* Ab = A8 + (size_t)R0 * C_DIM;

  // ---- stage A once: 16 octets (8 rows x 640 B = 5120 B = 5 instr each),
  // XOR-swizzled quads within 8-quad (128 B) groups, swizzle on source side.
#pragma unroll
  for (int i = 0; i < 10; ++i) {
    const int id = wv * 10 + i;             // 80 instructions total
    const int oct = id / 5, i2 = id % 5;
    const int lin = i2 * 64 + lane;
    const int row = lin / 40;               // 0..7 within octet
    const int quad = lin % 40;
    const int sq = (quad & ~7) | ((quad & 7) ^ (row & 7));
    glds16(Ab + (unsigned)(oct * 5120 + row * 640 + sq * 16),
           As + oct * 5120 + i2 * 1024);
  }

  // ---- B staging: strip = 8 rows x 128 B = 1 KB per instruction;
  // 32 strips per phase, 4 per wave. Source-side XOR swizzle.
  const unsigned brow =
      (unsigned)((lane >> 3) * 640 + (((lane & 7) ^ (lane >> 3)) * 16));
#pragma unroll
  for (int j = 0; j < 4; ++j) {             // prologue: phase 0 -> Bs[0]
    const int st = wv * 4 + j;
    glds16(Sway + (unsigned)st * (8 * 640) + brow, Bs[0] + st * 1024);
  }

  // ---- precomputed frag LDS offsets (b128, swizzled) ----
  // frag for (row, slice s): 16 B at logical quad 2s+h -> phys (2s+h)^(row&7)
  int aAddr[2][4], bAddr[2][4];
#pragma unroll
  for (int s = 0; s < 4; ++s) {
    const int pq = ((2 * s + h) ^ (r5 & 7)) * 16;
#pragma unroll
    for (int mi = 0; mi < 2; ++mi)
      aAddr[mi][s] = (wmB + mi * 32 + r5) * 640 + pq;
#pragma unroll
    for (int ni = 0; ni < 2; ++ni)
      bAddr[ni][s] = (wnB + ni * 32 + r5) * 128 + pq;
  }

  i32x16 acc[2][2];
#pragma unroll
  for (int mi = 0; mi < 2; ++mi)
#pragma unroll
    for (int ni = 0; ni < 2; ++ni)
#pragma unroll
      for (int g = 0; g < 16; ++g) acc[mi][ni][g] = 0;

  int t0[32], t1[32], t2[32];               // per-lane top-3, 32 row slots
#pragma unroll
  for (int r = 0; r < 32; ++r) { t0[r] = NEGINF; t1[r] = NEGINF; t2[r] = NEGINF; }

  int p = 0;
  for (int nt = 0; nt < NT; ++nt) {
#pragma unroll
    for (int kt = 0; kt < 5; ++kt) {
      __syncthreads();  // Bs[p] complete (prefetched last phase); Bs[p^1] free

      if (!(nt == NT - 1 && kt == 4)) {     // prefetch next phase -> Bs[p^1]
        const int nt1 = (kt == 4) ? nt + 1 : nt;
        const int kt1 = (kt == 4) ? 0 : kt + 1;
        const unsigned off =
            (unsigned)nt1 * (BN * C_DIM) + (unsigned)(kt1 * 128);
#pragma unroll
        for (int j = 0; j < 4; ++j) {
          const int st = wv * 4 + j;
          glds16(Sway + (unsigned)st * (8 * 640) + brow + off,
                 Bs[p ^ 1] + st * 1024);
        }
      }

      const u8* Bp = Bs[p];
      const int ka = kt * 128;
#pragma unroll
      for (int s = 0; s < 4; ++s) {
        const i32x4 a0 = *(const i32x4*)(As + aAddr[0][s] + ka);
        const i32x4 a1 = *(const i32x4*)(As + aAddr[1][s] + ka);
        const i32x4 b0 = *(const i32x4*)(Bp + bAddr[0][s]);
        const i32x4 b1 = *(const i32x4*)(Bp + bAddr[1][s]);
        acc[0][0] = __builtin_amdgcn_mfma_i32_32x32x32_i8(a0, b0, acc[0][0], 0, 0, 0);
        acc[1][0] = __builtin_amdgcn_mfma_i32_32x32x32_i8(a1, b0, acc[1][0], 0, 0, 0);
        acc[0][1] = __builtin_amdgcn_mfma_i32_32x32x32_i8(a0, b1, acc[0][1], 0, 0, 0);
        acc[1][1] = __builtin_amdgcn_mfma_i32_32x32x32_i8(a1, b1, acc[1][1], 0, 0, 0);
      }
      p ^= 1;
    }

    // end of nt: branchless int top-3 insert, re-zero acc.
    // C/D: col = lane&31 (-> n), row = (g&3) + 8*(g>>2) + 4*h (+ mi*32).
    const bool lastT = (nt == NT - 1);
#pragma unroll
    for (int ni = 0; ni < 2; ++ni) {
      const int ncol = nt * BN + wnB + ni * 32 + r5;
      const bool bad = lastT && (ncol >= NWAY);
#pragma unroll
      for (int mi = 0; mi < 2; ++mi)
#pragma unroll
        for (int g = 0; g < 16; ++g) {
          int v = acc[mi][ni][g];
          if (bad) v = NEGINF;
          const int r = mi * 16 + g;
          t2[r] = max(t2[r], min(v, t1[r]));
          t1[r] = max(t1[r], min(v, t0[r]));
          t0[r] = max(t0[r], v);
          acc[mi][ni][g] = 0;
        }
    }
  }

  // ---- partial butterfly over column-lanes d=1,2 (cheap), then LDS merge.
#pragma unroll
  for (int d = 1; d <= 2; d <<= 1) {
#pragma unroll
    for (int r = 0; r < 32; ++r) {
      const int o0 = __shfl_xor(t0[r], d);
      const int o1 = __shfl_xor(t1[r], d);
      const int o2 = __shfl_xor(t2[r], d);
      t2[r] = max(t2[r], min(o0, t1[r]));
      t1[r] = max(t1[r], min(o0, t0[r]));
      t0[r] = max(t0[r], o0);
      t2[r] = max(t2[r], min(o1, t1[r]));
      t1[r] = max(t1[r], min(o1, t0[r]));
      t0[r] = max(t0[r], o1);
      t2[r] = max(t2[r], min(o2, t1[r]));
      t1[r] = max(t1[r], min(o2, t0[r]));
      t0[r] = max(t0[r], o2);
    }
  }

  // dump 32 partials/row (4 nq x 8 col-groups) to LDS aliased over Bs (64 KB)
  __syncthreads();                          // all B-tile reads complete
  int* part = (int*)&Bs[0][0];              // part[row][j] : 16 B each
  if ((r5 & 3) == 0) {
    const int nq = wv & 3;
    const int grp = nq * 8 + (r5 >> 2);
#pragma unroll
    for (int r = 0; r < 32; ++r) {
      const int mi = r >> 4, g = r & 15;
      const int row_local = wmB + mi * 32 + (g & 3) + 8 * (g >> 2) + 4 * h;
      i32x4 v;
      v[0] = t0[r]; v[1] = t1[r]; v[2] = t2[r]; v[3] = NEGINF;
      *(i32x4*)&part[(row_local * 32 + grp) * 4] = v;
    }
  }
  __syncthreads();
  if (tid < MCH) {
    const int grow = R0 + tid;
    if (grow < MROWS) {
      int a0 = NEGINF, a1 = NEGINF, a2 = NEGINF;
#pragma unroll 4
      for (int j = 0; j < 32; ++j) {
        const int jj = (j + tid) & 31;      // bank-spread rotation
        const i32x4 v = *(const i32x4*)&part[(tid * 32 + jj) * 4];
        a2 = max(a2, min(v[0], a1)); a1 = max(a1, min(v[0], a0)); a0 = max(a0, v[0]);
        a2 = max(a2, min(v[1], a1)); a1 = max(a1, min(v[1], a0)); a0 = max(a0, v[1]);
        a2 = max(a2, min(v[2], a1)); a1 = max(a1, min(v[2], a0)); a0 = max(a0, v[2]);
      }
      const float rs = (float)(a0 + a1 + a2) * INV_Q2;
      const int qq = grow / HW_DIM;
      atomicAdd(&qsum[qq - (R0 / HW_DIM)], rs);     // block spans <= 2 q's
    }
  }
  __syncthreads();
  if (tid < 2) {
    const int qq = R0 / HW_DIM + tid;
    if (qq < QN) atomicAdd(out + qq * WAYS + way, qsum[tid]);
  }
}

// ---------------------------------------------------------------------------
extern "C" void kernel_launch(void* const* d_in, const int* in_sizes, int n_in,
                              void* d_out, int out_size, void* d_ws, size_t ws_size,
                              hipStream_t stream) {
  const float* x1 = (const float*)d_in[0];
  const float* x2 = (const float*)d_in[1];
  float* out = (float*)d_out;
  u8* A8 = (u8*)d_ws;                                        // MPAD x 640 i8
  u8* S8 = (u8*)d_ws + (size_t)MPAD * C_DIM;                 // 5 x NPAD x 640

  hipLaunchKernelGGL(zero_pad, dim3(1432), dim3(256), 0, stream, A8, S8, out);
  hipLaunchKernelGGL(prep_norm_transpose, dim3(QN * 7), dim3(256), 0, stream,
                     x1, A8, 0);
  hipLaunchKernelGGL(prep_norm_transpose, dim3(SN * 7), dim3(256), 0, stream,
                     x2, S8, 1);
  hipLaunchKernelGGL(simtopk, dim3(WAYS * MBLK), dim3(512), 0, stream,
                     A8, S8, out);
}

// Round 7
// 538.151 us; speedup vs baseline: 1.7319x; 1.0412x over previous
//
#include <hip/hip_runtime.h>

typedef unsigned char u8;
typedef int i32x4 __attribute__((ext_vector_type(4)));
typedef int i32x16 __attribute__((ext_vector_type(16)));

#define C_DIM 640
#define HW_DIM 441
#define QN 75
#define SN 25
#define WAYS 5
#define MROWS 33075     // 75*441
#define MCH   64        // m rows per block
#define MBLK  517       // ceil(33075/64)
#define MPAD  33088     // MBLK*MCH
#define NWAY  2205      // 5*441
#define NPAD  2304      // 9*256
#define BN    256       // block n-tile
#define NT    9         // NPAD/BN
#define INV_Q2 (1.0f / 16129.0f)   // 1/127^2
#define NEGINF (-2147483647 - 1)

__device__ __forceinline__ void glds16(const void* g, void* l) {
  __builtin_amdgcn_global_load_lds(
      (__attribute__((address_space(1))) unsigned int*)g,
      (__attribute__((address_space(3))) unsigned int*)l, 16, 0, 0);
}

// ---------------------------------------------------------------------------
// Zero pad rows of A/B (int8 bytes) and the output accumulator.
// ---------------------------------------------------------------------------
__global__ void zero_pad(u8* __restrict__ A8, u8* __restrict__ S8,
                         float* __restrict__ out) {
  int i = blockIdx.x * 256 + threadIdx.x;
  if (i < 8320) {                                   // (MPAD-MROWS)*640 bytes
    A8[(size_t)MROWS * C_DIM + i] = 0;
    return;
  }
  i -= 8320;
  if (i < 316800) {                                 // 5*(NPAD-NWAY)*640 bytes
    const int w = i / 63360;
    const int r = i % 63360;
    S8[((size_t)w * NPAD + NWAY) * C_DIM + r] = 0;
    return;
  }
  i -= 316800;
  if (i < QN * WAYS) out[i] = 0.f;
}

// ---------------------------------------------------------------------------
// Normalize each (img, hw) descriptor over C, scale by 127, emit int8,
// transposed to [row][c] (c contiguous, 640 B/row). (unchanged from R6)
// ---------------------------------------------------------------------------
__global__ __launch_bounds__(256)
void prep_norm_transpose(const float* __restrict__ src, u8* __restrict__ dst,
                         int support) {
  const int bid = blockIdx.x;
  const int img = bid / 7;
  const int mt = bid % 7;
  const int m0 = mt * 64;
  const int t = threadIdx.x;
  const int mloc = t & 63;
  const int cpart = t >> 6;                 // 0..3
  const int m = m0 + mloc;
  const int m_eff = (m < HW_DIM) ? m : (HW_DIM - 1);
  const float* base = src + (size_t)img * (C_DIM * HW_DIM);

  float ss = 0.f;
  const int c0 = cpart * 160;
  for (int c = c0; c < c0 + 160; ++c) {
    float v = base[(size_t)c * HW_DIM + m_eff];
    ss += v * v;
  }
  __shared__ float red[256];
  __shared__ float inv[64];
  red[t] = ss;
  __syncthreads();
  if (t < 64) {
    float s4 = red[t] + red[t + 64] + red[t + 128] + red[t + 192];
    inv[t] = rsqrtf(s4) * 127.0f;
  }
  __syncthreads();

  size_t drow0;
  if (support) {
    const int w = img / 5, shot = img % 5;
    drow0 = (size_t)w * NPAD + (size_t)shot * HW_DIM;
  } else {
    drow0 = (size_t)img * HW_DIM;
  }

  __shared__ __align__(16) u8 T[64][80];    // 64 data + 16 pad per row
  const float iv = inv[mloc];
  const int mw = t >> 2;
  const int cg = t & 3;
  const int m_out = m0 + mw;

  for (int ct = 0; ct < 10; ++ct) {
    int q[16];
#pragma unroll
    for (int ci = 0; ci < 16; ++ci) {
      const int c = ct * 64 + cpart * 16 + ci;
      q[ci] = __float2int_rn(base[(size_t)c * HW_DIM + m_eff] * iv);
    }
    __syncthreads();                        // previous tile fully consumed
    uint4 w;
    w.x = (q[0] & 255) | ((q[1] & 255) << 8) | ((q[2] & 255) << 16) | ((q[3] & 255) << 24);
    w.y = (q[4] & 255) | ((q[5] & 255) << 8) | ((q[6] & 255) << 16) | ((q[7] & 255) << 24);
    w.z = (q[8] & 255) | ((q[9] & 255) << 8) | ((q[10] & 255) << 16) | ((q[11] & 255) << 24);
    w.w = (q[12] & 255) | ((q[13] & 255) << 8) | ((q[14] & 255) << 16) | ((q[15] & 255) << 24);
    *(uint4*)&T[mloc][cpart * 16] = w;
    __syncthreads();
    if (m_out < HW_DIM) {
      const uint4 v = *(const uint4*)&T[mw][cg * 16];
      *(uint4*)(dst + (drow0 + m_out) * C_DIM + ct * 64 + cg * 16) = v;
    }
  }
}

// ---------------------------------------------------------------------------
// Fused cosine-sim GEMM (int8 mfma_i32_32x32x32) + per-row top-3 + sum.
// Round-7 structure:
//  - A is REGISTER-resident: each lane holds its row's full K=640 as 20
//    i32x4 frags (80 VGPR), loaded once from global. No A staging, no A
//    LDS reads (this was half of all LDS traffic).
//  - 256-thread blocks (4 waves, 2m x 2n; wave tile 32x128), block 64x256.
//  - LDS = B double buffer only (2 x 32 KB) -> 2 blocks/CU = two
//    independent barrier domains whose read/MFMA bursts interleave.
//  - B prefetched one phase ahead (R5/R6 proven scheme), b128 frag reads
//    XOR-swizzled = conflict-free.
// Grid: 5 ways * 517 m-chunks (5.05 occupancy rounds).
// ---------------------------------------------------------------------------
__global__ __launch_bounds__(256, 2)
void simtopk(const u8* __restrict__ A8, const u8* __restrict__ S8,
             float* __restrict__ out) {
  __shared__ __align__(16) u8 Bs[2][BN * 128];      // 64 KB B double buffer
  __shared__ float qsum[2];

  const int bid = blockIdx.x;
  const int way = bid / MBLK;
  const int mc = bid % MBLK;
  const int R0 = mc * MCH;
  const int tid = threadIdx.x;
  const int lane = tid & 63;
  const int wv = tid >> 6;                  // 0..3
  const int wm = (wv >> 1) * 32;            // wave m base: 0 / 32
  const int nh = wv & 1;                    // n-half: 0 / 1
  const int wnB = nh * 128;
  const int r5 = lane & 31;
  const int h = lane >> 5;                  // k-half selector

  if (tid < 2) qsum[tid] = 0.f;

  const u8* Sway = S8 + (size_t)way * NPAD * C_DIM;

  // ---- A into registers: lane (r5,h) owns row R0+wm+r5, k-bytes
  // ks*32 + h*16 .. +16 for ks = 0..19  (R6-verified logical layout).
  i32x4 a[20];
  {
    const u8* Arow = A8 + (size_t)(R0 + wm + r5) * C_DIM + h * 16;
#pragma unroll
    for (int ks = 0; ks < 20; ++ks)
      a[ks] = *(const i32x4*)(Arow + ks * 32);
  }

  // ---- B staging: strip = 8 rows x 128 B = 1 KB per instruction;
  // 32 strips per phase, 8 per wave. Source-side XOR swizzle.
  const unsigned brow =
      (unsigned)((lane >> 3) * 640 + (((lane & 7) ^ (lane >> 3)) * 16));
#pragma unroll
  for (int j = 0; j < 8; ++j) {             // prologue: phase 0 -> Bs[0]
    const int st = wv * 8 + j;
    glds16(Sway + (unsigned)st * (8 * 640) + brow, Bs[0] + st * 1024);
  }

  // ---- precomputed B-frag LDS offsets (b128, swizzled, conflict-free) ----
  int bBase[4], pqs[4];
#pragma unroll
  for (int ni = 0; ni < 4; ++ni)
    bBase[ni] = (wnB + ni * 32 + r5) * 128;
#pragma unroll
  for (int s = 0; s < 4; ++s)
    pqs[s] = ((2 * s + h) ^ (r5 & 7)) * 16;

  i32x16 acc[4];
#pragma unroll
  for (int ni = 0; ni < 4; ++ni)
#pragma unroll
    for (int g = 0; g < 16; ++g) acc[ni][g] = 0;

  int t0[16], t1[16], t2[16];               // per-lane top-3, 16 row slots
#pragma unroll
  for (int r = 0; r < 16; ++r) { t0[r] = NEGINF; t1[r] = NEGINF; t2[r] = NEGINF; }

  int p = 0;
  for (int nt = 0; nt < NT; ++nt) {
#pragma unroll
    for (int kt = 0; kt < 5; ++kt) {
      __syncthreads();  // Bs[p] ready (prefetched last phase); Bs[p^1] free

      if (!(nt == NT - 1 && kt == 4)) {     // prefetch next phase -> Bs[p^1]
        const int nt1 = (kt == 4) ? nt + 1 : nt;
        const int kt1 = (kt == 4) ? 0 : kt + 1;
        const unsigned off =
            (unsigned)nt1 * (BN * C_DIM) + (unsigned)(kt1 * 128);
#pragma unroll
        for (int j = 0; j < 8; ++j) {
          const int st = wv * 8 + j;
          glds16(Sway + (unsigned)st * (8 * 640) + brow + off,
                 Bs[p ^ 1] + st * 1024);
        }
      }

      const u8* Bp = Bs[p];
#pragma unroll
      for (int s = 0; s < 4; ++s) {
        const i32x4 av = a[kt * 4 + s];
        i32x4 b0 = *(const i32x4*)(Bp + bBase[0] + pqs[s]);
        i32x4 b1 = *(const i32x4*)(Bp + bBase[1] + pqs[s]);
        i32x4 b2 = *(const i32x4*)(Bp + bBase[2] + pqs[s]);
        i32x4 b3 = *(const i32x4*)(Bp + bBase[3] + pqs[s]);
        acc[0] = __builtin_amdgcn_mfma_i32_32x32x32_i8(av, b0, acc[0], 0, 0, 0);
        acc[1] = __builtin_amdgcn_mfma_i32_32x32x32_i8(av, b1, acc[1], 0, 0, 0);
        acc[2] = __builtin_amdgcn_mfma_i32_32x32x32_i8(av, b2, acc[2], 0, 0, 0);
        acc[3] = __builtin_amdgcn_mfma_i32_32x32x32_i8(av, b3, acc[3], 0, 0, 0);
      }
      p ^= 1;
    }

    // end of nt: branchless int top-3 insert, re-zero acc.
    // C/D 32x32: col = r5 (-> n), row = (g&3) + 8*(g>>2) + 4*h (+ wm).
    const bool lastT = (nt == NT - 1);
#pragma unroll
    for (int ni = 0; ni < 4; ++ni) {
      const int ncol = nt * BN + wnB + ni * 32 + r5;
      const bool bad = lastT && (ncol >= NWAY);
#pragma unroll
      for (int g = 0; g < 16; ++g) {
        int v = acc[ni][g];
        if (bad) v = NEGINF;
        t2[g] = max(t2[g], min(v, t1[g]));
        t1[g] = max(t1[g], min(v, t0[g]));
        t0[g] = max(t0[g], v);
        acc[ni][g] = 0;
      }
    }
  }

  // ---- partial butterfly over column-lanes d=1,2 (stays in 32-lane half)
#pragma unroll
  for (int d = 1; d <= 2; d <<= 1) {
#pragma unroll
    for (int r = 0; r < 16; ++r) {
      const int o0 = __shfl_xor(t0[r], d);
      const int o1 = __shfl_xor(t1[r], d);
      const int o2 = __shfl_xor(t2[r], d);
      t2[r] = max(t2[r], min(o0, t1[r]));
      t1[r] = max(t1[r], min(o0, t0[r]));
      t0[r] = max(t0[r], o0);
      t2[r] = max(t2[r], min(o1, t1[r]));
      t1[r] = max(t1[r], min(o1, t0[r]));
      t0[r] = max(t0[r], o1);
      t2[r] = max(t2[r], min(o2, t1[r]));
      t1[r] = max(t1[r], min(o2, t0[r]));
      t0[r] = max(t0[r], o2);
    }
  }

  // dump 16 partials/row (2 nh x 8 col-groups) to LDS aliased over Bs
  __syncthreads();                          // all B-tile reads complete
  int* part = (int*)&Bs[0][0];              // part[grp][row][4] : 16 KB
  if ((r5 & 3) == 0) {
    const int grp = nh * 8 + (r5 >> 2);     // 0..15
#pragma unroll
    for (int r = 0; r < 16; ++r) {
      const int row_local = wm + (r & 3) + 8 * (r >> 2) + 4 * h;
      i32x4 v;
      v[0] = t0[r]; v[1] = t1[r]; v[2] = t2[r]; v[3] = NEGINF;
      *(i32x4*)&part[(grp * MCH + row_local) * 4] = v;
    }
  }
  __syncthreads();
  if (tid < MCH) {
    const int grow = R0 + tid;
    if (grow < MROWS) {
      int a0 = NEGINF, a1 = NEGINF, a2 = NEGINF;
#pragma unroll 4
      for (int g = 0; g < 16; ++g) {
        const i32x4 v = *(const i32x4*)&part[(g * MCH + tid) * 4];
        a2 = max(a2, min(v[0], a1)); a1 = max(a1, min(v[0], a0)); a0 = max(a0, v[0]);
        a2 = max(a2, min(v[1], a1)); a1 = max(a1, min(v[1], a0)); a0 = max(a0, v[1]);
        a2 = max(a2, min(v[2], a1)); a1 = max(a1, min(v[2], a0)); a0 = max(a0, v[2]);
      }
      const float rs = (float)(a0 + a1 + a2) * INV_Q2;
      const int qq = grow / HW_DIM;
      atomicAdd(&qsum[qq - (R0 / HW_DIM)], rs);     // block spans <= 2 q's
    }
  }
  __syncthreads();
  if (tid < 2) {
    const int qq = R0 / HW_DIM + tid;
    if (qq < QN) atomicAdd(out + qq * WAYS + way, qsum[tid]);
  }
}

// ---------------------------------------------------------------------------
extern "C" void kernel_launch(void* const* d_in, const int* in_sizes, int n_in,
                              void* d_out, int out_size, void* d_ws, size_t ws_size,
                              hipStream_t stream) {
  const float* x1 = (const float*)d_in[0];
  const float* x2 = (const float*)d_in[1];
  float* out = (float*)d_out;
  u8* A8 = (u8*)d_ws;                                        // MPAD x 640 i8
  u8* S8 = (u8*)d_ws + (size_t)MPAD * C_DIM;                 // 5 x NPAD x 640

  hipLaunchKernelGGL(zero_pad, dim3(1272), dim3(256), 0, stream, A8, S8, out);
  hipLaunchKernelGGL(prep_norm_transpose, dim3(QN * 7), dim3(256), 0, stream,
                     x1, A8, 0);
  hipLaunchKernelGGL(prep_norm_transpose, dim3(SN * 7), dim3(256), 0, stream,
                     x2, S8, 1);
  hipLaunchKernelGGL(simtopk, dim3(WAYS * MBLK), dim3(256), 0, stream,
                     A8, S8, out);
}